// Round 1
// baseline (560.071 us; speedup 1.0000x reference)
//
#include <hip/hip_runtime.h>

#define NTOK  131072
#define DDIM  192
#define KMEM  128
#define TWOD  384

// ---------------------------------------------------------------------------
// prep: L2-normalize mem_bank rows; precompute GLU(mem_bank) table (K distinct
// rows only -- the full N x 2D GEMM in the reference collapses to a lookup).
// ---------------------------------------------------------------------------
__global__ __launch_bounds__(192) void prep_kernel(
    const float* __restrict__ mb, const float* __restrict__ W,
    const float* __restrict__ bias, float* __restrict__ mem_n,
    float* __restrict__ tab) {
  __shared__ float row[DDIM];
  __shared__ float red[DDIM];
  __shared__ float s_rn;
  const int k = blockIdx.x;
  const int t = threadIdx.x;  // 0..191
  float m = mb[k * DDIM + t];
  row[t] = m;
  red[t] = m * m;
  __syncthreads();
  if (t == 0) {
    float s = 0.f;
    for (int i = 0; i < DDIM; ++i) s += red[i];
    s_rn = 1.0f / sqrtf(fmaxf(s, 1e-12f));
  }
  __syncthreads();
  mem_n[k * DDIM + t] = m * s_rn;
  float a = bias[t], g = bias[DDIM + t];
  for (int d = 0; d < DDIM; ++d) {
    float r = row[d];
    a = fmaf(r, W[d * TWOD + t], a);
    g = fmaf(r, W[d * TWOD + DDIM + t], g);
  }
  float sg = 1.0f / (1.0f + expf(-g));
  tab[k * DDIM + t] = a * sg;
}

// ---------------------------------------------------------------------------
// sim: E[n][k] = exp(cos_sim / 0.05), plus per-block row partials R0[k].
// 128 tokens x 128 codes per block; 8x8 register tile per thread.
// Rows assigned strided by 16 so wave lanes hit consecutive LDS rows:
// stride 36 floats -> bank stride 4 -> worst 2-way conflict (free).
// ---------------------------------------------------------------------------
__global__ __launch_bounds__(256) void sim_kernel(
    const float* __restrict__ proj, const float* __restrict__ mem_n,
    float* __restrict__ E, double* __restrict__ Rp) {
  __shared__ float xs[128][36];
  __shared__ float ms[128][36];
  __shared__ float rred[16][KMEM];
  const int tid = threadIdx.x;
  const long n0 = (long)blockIdx.x * 128;
  const int tg = tid >> 4;  // tokens tg + 16*i
  const int kg = tid & 15;  // codes  kg + 16*j
  float acc[8][8];
  float nrm[8];
#pragma unroll
  for (int i = 0; i < 8; ++i) {
    nrm[i] = 0.f;
#pragma unroll
    for (int j = 0; j < 8; ++j) acc[i][j] = 0.f;
  }
  for (int dc = 0; dc < DDIM; dc += 32) {
#pragma unroll
    for (int j = 0; j < 4; ++j) {
      const int l = tid + 256 * j;   // 1024 float4 per tile
      const int t = l >> 3;          // 0..127
      const int dq = (l & 7) * 4;    // 0..28
      *(float4*)&xs[t][dq] = *(const float4*)&proj[(n0 + t) * DDIM + dc + dq];
      *(float4*)&ms[t][dq] = *(const float4*)&mem_n[t * DDIM + dc + dq];
    }
    __syncthreads();
#pragma unroll
    for (int dq = 0; dq < 32; dq += 4) {
      float4 xv[8];
#pragma unroll
      for (int i = 0; i < 8; ++i) {
        xv[i] = *(const float4*)&xs[tg + 16 * i][dq];
        nrm[i] = fmaf(xv[i].x, xv[i].x, nrm[i]);
        nrm[i] = fmaf(xv[i].y, xv[i].y, nrm[i]);
        nrm[i] = fmaf(xv[i].z, xv[i].z, nrm[i]);
        nrm[i] = fmaf(xv[i].w, xv[i].w, nrm[i]);
      }
#pragma unroll
      for (int j = 0; j < 8; ++j) {
        const float4 mv = *(const float4*)&ms[kg + 16 * j][dq];
#pragma unroll
        for (int i = 0; i < 8; ++i) {
          acc[i][j] = fmaf(xv[i].x, mv.x, acc[i][j]);
          acc[i][j] = fmaf(xv[i].y, mv.y, acc[i][j]);
          acc[i][j] = fmaf(xv[i].z, mv.z, acc[i][j]);
          acc[i][j] = fmaf(xv[i].w, mv.w, acc[i][j]);
        }
      }
    }
    __syncthreads();
  }
  // epilogue: logits -> E (match np: fp32 division by 0.05f, precise expf)
  float rsum[8];
#pragma unroll
  for (int j = 0; j < 8; ++j) rsum[j] = 0.f;
#pragma unroll
  for (int i = 0; i < 8; ++i) {
    const long n = n0 + tg + 16 * i;
    const float rn = 1.0f / sqrtf(fmaxf(nrm[i], 1e-12f));
#pragma unroll
    for (int j = 0; j < 8; ++j) {
      const float sim = acc[i][j] * rn;
      const float e = expf(sim / 0.05f);
      rsum[j] += e;
      E[n * KMEM + kg + 16 * j] = e;
    }
  }
#pragma unroll
  for (int j = 0; j < 8; ++j) rred[tg][kg + 16 * j] = rsum[j];
  __syncthreads();
  if (tid < KMEM) {
    float s = 0.f;
#pragma unroll
    for (int g = 0; g < 16; ++g) s += rred[g][tid];
    Rp[(long)blockIdx.x * KMEM + tid] = (double)s;
  }
}

// ---------------------------------------------------------------------------
// u update: u[k] = 1 / (K * sum_b Rp[b][k]). Deterministic fixed-order fp64.
// ---------------------------------------------------------------------------
__global__ __launch_bounds__(1024) void u_kernel(const double* __restrict__ Rp,
                                                 int nblk,
                                                 float* __restrict__ u) {
  __shared__ double part[8][KMEM];
  const int k = threadIdx.x & 127;
  const int p = threadIdx.x >> 7;  // 0..7
  const int per = nblk >> 3;
  const int b0 = p * per;
  double s = 0.0;
  for (int b = 0; b < per; ++b) s += Rp[(long)(b0 + b) * KMEM + k];
  part[p][k] = s;
  __syncthreads();
  if (threadIdx.x < KMEM) {
    double t = 0.0;
#pragma unroll
    for (int g = 0; g < 8; ++g) t += part[g][k];
    u[k] = (float)(1.0 / (128.0 * t));
  }
}

// ---------------------------------------------------------------------------
// cv: per token, colsum C = dot(E_row, u); v = 1/(N*C); accumulate next row
// sums R[k] += E[n][k]*v. One fused pass per Sinkhorn iteration.
// ---------------------------------------------------------------------------
__global__ __launch_bounds__(256) void cv_kernel(const float* __restrict__ E,
                                                 const float* __restrict__ u,
                                                 double* __restrict__ Rp) {
  __shared__ double R2[8][KMEM];
  const int tid = threadIdx.x;
  const int kq = (tid & 31) * 4;
  const int tg = tid >> 5;
  const float4 u4 = *(const float4*)&u[kq];
  double r0 = 0, r1 = 0, r2 = 0, r3 = 0;
  const long n0 = (long)blockIdx.x * 512;
  for (int it = 0; it < 64; ++it) {
    const long n = n0 + it * 8 + tg;
    const float4 e = *(const float4*)&E[n * KMEM + kq];
    double c = (double)e.x * u4.x + (double)e.y * u4.y +
               (double)e.z * u4.z + (double)e.w * u4.w;
#pragma unroll
    for (int off = 1; off < 32; off <<= 1) c += __shfl_xor(c, off);
    const float v = (float)(1.0 / (131072.0 * c));
    r0 += (double)(e.x * v);
    r1 += (double)(e.y * v);
    r2 += (double)(e.z * v);
    r3 += (double)(e.w * v);
  }
  R2[tg][kq + 0] = r0;
  R2[tg][kq + 1] = r1;
  R2[tg][kq + 2] = r2;
  R2[tg][kq + 3] = r3;
  __syncthreads();
  if (tid < KMEM) {
    double s = 0.0;
#pragma unroll
    for (int g = 0; g < 8; ++g) s += R2[g][tid];
    Rp[(long)blockIdx.x * KMEM + tid] = s;
  }
}

// ---------------------------------------------------------------------------
// argmax over k of E[n][k]*u[k] (col factors drop out of argmax).
// First-index tiebreak matches np.argmax.
// ---------------------------------------------------------------------------
__global__ __launch_bounds__(256) void argmax_kernel(
    const float* __restrict__ E, const float* __restrict__ u,
    int* __restrict__ idx) {
  const int tid = threadIdx.x;
  const int kq = (tid & 31) * 4;
  const int tg = tid >> 5;
  const float4 u4 = *(const float4*)&u[kq];
  const long n0 = (long)blockIdx.x * 512;
  for (int it = 0; it < 64; ++it) {
    const long n = n0 + it * 8 + tg;
    const float4 e = *(const float4*)&E[n * KMEM + kq];
    float bv = e.x * u4.x;
    int bi = kq;
    float p = e.y * u4.y;
    if (p > bv) { bv = p; bi = kq + 1; }
    p = e.z * u4.z;
    if (p > bv) { bv = p; bi = kq + 2; }
    p = e.w * u4.w;
    if (p > bv) { bv = p; bi = kq + 3; }
#pragma unroll
    for (int off = 1; off < 32; off <<= 1) {
      const float ov = __shfl_xor(bv, off);
      const int oi = __shfl_xor(bi, off);
      if (ov > bv || (ov == bv && oi < bi)) { bv = ov; bi = oi; }
    }
    if ((tid & 31) == 0) idx[n] = bi;
  }
}

// ---------------------------------------------------------------------------
// out = (proj + glu_table[idx]) * 0.5, fully coalesced float4 stream.
// ---------------------------------------------------------------------------
__global__ __launch_bounds__(256) void out_kernel(
    const float* __restrict__ proj, const float* __restrict__ tab,
    const int* __restrict__ idx, float* __restrict__ out) {
  const long base = (long)blockIdx.x * 3072;
#pragma unroll
  for (int j = 0; j < 12; ++j) {
    const long f = base + j * 256 + threadIdx.x;  // float4 index
    const int t = (int)(f / 48);                  // 48 float4 per token row
    const int r = (int)(f - (long)t * 48);
    const int id = idx[t];
    const float4 p = *(const float4*)&proj[f * 4];
    const float4 tb = *(const float4*)&tab[id * DDIM + r * 4];
    float4 o;
    o.x = (p.x + tb.x) * 0.5f;
    o.y = (p.y + tb.y) * 0.5f;
    o.z = (p.z + tb.z) * 0.5f;
    o.w = (p.w + tb.w) * 0.5f;
    *(float4*)&out[f * 4] = o;
  }
}

extern "C" void kernel_launch(void* const* d_in, const int* in_sizes, int n_in,
                              void* d_out, int out_size, void* d_ws,
                              size_t ws_size, hipStream_t stream) {
  const float* proj = (const float*)d_in[0];
  const float* mb = (const float*)d_in[1];
  const float* W = (const float*)d_in[2];
  const float* bias = (const float*)d_in[3];
  float* out = (float*)d_out;
  char* ws = (char*)d_ws;
  // ws layout (~2.3 MB total)
  float* mem_n = (float*)(ws);                // 98304 B
  float* tab = (float*)(ws + 98304);          // 98304 B
  double* Rp0 = (double*)(ws + 196608);       // 1024*128*8 = 1 MiB
  double* Rp1 = (double*)(ws + 1245184);      // 256 KiB
  double* Rp2 = (double*)(ws + 1507328);      // 256 KiB
  float* u1 = (float*)(ws + 1769472);
  float* u2 = (float*)(ws + 1769984);
  float* u3 = (float*)(ws + 1770496);
  int* idx = (int*)(ws + 1771008);            // 512 KiB
  // E (N x K fp32 = 64 MiB) lives in d_out scratch; consumed before out write.
  float* E = out;

  prep_kernel<<<KMEM, DDIM, 0, stream>>>(mb, W, bias, mem_n, tab);
  sim_kernel<<<1024, 256, 0, stream>>>(proj, mem_n, E, Rp0);
  u_kernel<<<1, 1024, 0, stream>>>(Rp0, 1024, u1);
  cv_kernel<<<256, 256, 0, stream>>>(E, u1, Rp1);
  u_kernel<<<1, 1024, 0, stream>>>(Rp1, 256, u2);
  cv_kernel<<<256, 256, 0, stream>>>(E, u2, Rp2);
  u_kernel<<<1, 1024, 0, stream>>>(Rp2, 256, u3);
  argmax_kernel<<<256, 256, 0, stream>>>(E, u3, idx);
  out_kernel<<<2048, 256, 0, stream>>>(proj, tab, idx, out);
}

// Round 2
// 454.419 us; speedup vs baseline: 1.2325x; 1.2325x over previous
//
#include <hip/hip_runtime.h>

#define NTOK  131072
#define DDIM  192
#define KMEM  128
#define TWOD  384

typedef _Float16 half8 __attribute__((ext_vector_type(8)));
typedef float   floatx4 __attribute__((ext_vector_type(4)));

// ---------------------------------------------------------------------------
// prep: L2-normalize mem_bank rows -> fp16x2 split (hi, lo*4096) global arrays;
// precompute GLU(mem_bank) table (K distinct rows only).
// ---------------------------------------------------------------------------
__global__ __launch_bounds__(192) void prep_kernel(
    const float* __restrict__ mb, const float* __restrict__ W,
    const float* __restrict__ bias, _Float16* __restrict__ bhi,
    _Float16* __restrict__ blo, float* __restrict__ tab) {
  __shared__ float row[DDIM];
  __shared__ float red[DDIM];
  __shared__ float s_rn;
  const int k = blockIdx.x;
  const int t = threadIdx.x;  // 0..191
  float m = mb[k * DDIM + t];
  row[t] = m;
  red[t] = m * m;
  __syncthreads();
  if (t == 0) {
    float s = 0.f;
    for (int i = 0; i < DDIM; ++i) s += red[i];
    s_rn = 1.0f / sqrtf(fmaxf(s, 1e-12f));
  }
  __syncthreads();
  const float mn = m * s_rn;
  const _Float16 hh = (_Float16)mn;
  const float lo = (mn - (float)hh) * 4096.0f;
  bhi[k * DDIM + t] = hh;
  blo[k * DDIM + t] = (_Float16)lo;
  float a = bias[t], g = bias[DDIM + t];
  for (int d = 0; d < DDIM; ++d) {
    float r = row[d];
    a = fmaf(r, W[d * TWOD + t], a);
    g = fmaf(r, W[d * TWOD + DDIM + t], g);
  }
  float sg = 1.0f / (1.0f + expf(-g));
  tab[k * DDIM + t] = a * sg;
}

// ---------------------------------------------------------------------------
// sim: E[n][k] = exp(cos_sim/0.05) via fp16x2 MFMA (16x16x32_f16).
// Block tile 128 tokens x 128 codes; 4 waves as 2x2 of 64x64 wave-tiles;
// per wave 4x4 subtiles of 16x16. acc1 = hi*hi, acc2 = hi*lo' + lo'*hi
// (lo' = lo*2^12); sim = (acc1 + acc2*2^-12) * rn_token.
// LDS rows padded to 40 halfs (80 B) -> worst 2-way conflict on b128 frags.
// ---------------------------------------------------------------------------
#define LSTR 40
__global__ __launch_bounds__(256, 2) void sim_kernel(
    const float* __restrict__ proj, const _Float16* __restrict__ bhi_g,
    const _Float16* __restrict__ blo_g, float* __restrict__ E,
    double* __restrict__ Rp) {
  __shared__ _Float16 Ahi[128 * LSTR];
  __shared__ _Float16 Alo[128 * LSTR];
  __shared__ _Float16 Bhi[128 * LSTR];
  __shared__ _Float16 Blo[128 * LSTR];
  __shared__ float rn_s[128];
  __shared__ float red[4][64];
  const int tid = threadIdx.x;
  const int lane = tid & 63;
  const int wid = tid >> 6;
  const int tok_half = wid & 1;
  const int code_half = wid >> 1;
  const long n0 = (long)blockIdx.x * 128;
  const int st_tok = tid >> 1;   // staging: token row 0..127
  const int st_h = tid & 1;      // staging: which 16-float half of the chunk

  floatx4 acc1[4][4];
  floatx4 acc2[4][4];
#pragma unroll
  for (int i = 0; i < 4; ++i)
#pragma unroll
    for (int j = 0; j < 4; ++j) {
      acc1[i][j] = (floatx4)0.0f;
      acc2[i][j] = (floatx4)0.0f;
    }
  float nsq = 0.f;

  const int m_row = lane & 15;
  const int quad = lane >> 4;
  const int kcol = quad * 8;

  for (int c = 0; c < 6; ++c) {
    // ---- stage A (proj chunk, fp32 -> hi/lo halfs) ----
    {
      const float* src = &proj[(n0 + st_tok) * DDIM + c * 32 + st_h * 16];
      float4 p0 = *(const float4*)(src + 0);
      float4 p1 = *(const float4*)(src + 4);
      float4 p2 = *(const float4*)(src + 8);
      float4 p3 = *(const float4*)(src + 12);
      float xs[16] = {p0.x, p0.y, p0.z, p0.w, p1.x, p1.y, p1.z, p1.w,
                      p2.x, p2.y, p2.z, p2.w, p3.x, p3.y, p3.z, p3.w};
      half8 h0, h1, l0, l1;
#pragma unroll
      for (int i = 0; i < 8; ++i) {
        float x = xs[i];
        nsq = fmaf(x, x, nsq);
        _Float16 hh = (_Float16)x;
        h0[i] = hh;
        l0[i] = (_Float16)((x - (float)hh) * 4096.0f);
      }
#pragma unroll
      for (int i = 0; i < 8; ++i) {
        float x = xs[8 + i];
        nsq = fmaf(x, x, nsq);
        _Float16 hh = (_Float16)x;
        h1[i] = hh;
        l1[i] = (_Float16)((x - (float)hh) * 4096.0f);
      }
      const int lb = st_tok * LSTR + st_h * 16;
      *(half8*)&Ahi[lb] = h0;
      *(half8*)&Ahi[lb + 8] = h1;
      *(half8*)&Alo[lb] = l0;
      *(half8*)&Alo[lb + 8] = l1;
      // ---- stage B (preconverted halfs, straight copy) ----
      const int gb = st_tok * DDIM + c * 32 + st_h * 16;
      *(half8*)&Bhi[lb] = *(const half8*)&bhi_g[gb];
      *(half8*)&Bhi[lb + 8] = *(const half8*)&bhi_g[gb + 8];
      *(half8*)&Blo[lb] = *(const half8*)&blo_g[gb];
      *(half8*)&Blo[lb + 8] = *(const half8*)&blo_g[gb + 8];
    }
    __syncthreads();
    // ---- MFMA over this k-chunk (K=32, one 16x16x32 step) ----
    half8 a_hi[4], a_lo[4];
#pragma unroll
    for (int sm = 0; sm < 4; ++sm) {
      const int ar = (tok_half * 64 + sm * 16 + m_row) * LSTR + kcol;
      a_hi[sm] = *(const half8*)&Ahi[ar];
      a_lo[sm] = *(const half8*)&Alo[ar];
    }
#pragma unroll
    for (int sn = 0; sn < 4; ++sn) {
      const int br = (code_half * 64 + sn * 16 + m_row) * LSTR + kcol;
      half8 b_hi = *(const half8*)&Bhi[br];
      half8 b_lo = *(const half8*)&Blo[br];
#pragma unroll
      for (int sm = 0; sm < 4; ++sm) {
        acc1[sm][sn] =
            __builtin_amdgcn_mfma_f32_16x16x32_f16(a_hi[sm], b_hi, acc1[sm][sn], 0, 0, 0);
        acc2[sm][sn] =
            __builtin_amdgcn_mfma_f32_16x16x32_f16(a_hi[sm], b_lo, acc2[sm][sn], 0, 0, 0);
        acc2[sm][sn] =
            __builtin_amdgcn_mfma_f32_16x16x32_f16(a_lo[sm], b_hi, acc2[sm][sn], 0, 0, 0);
      }
    }
    __syncthreads();
  }
  // token norms: thread pair (t, t^1) covered complementary halves
  nsq += __shfl_xor(nsq, 1);
  if ((tid & 1) == 0) rn_s[st_tok] = 1.0f / sqrtf(fmaxf(nsq, 1e-12f));
  __syncthreads();

  // ---- epilogue: sim -> exp, store E, per-wave column sums ----
  float rcol[4] = {0.f, 0.f, 0.f, 0.f};
#pragma unroll
  for (int sm = 0; sm < 4; ++sm) {
    float rnr[4];
#pragma unroll
    for (int r = 0; r < 4; ++r)
      rnr[r] = rn_s[tok_half * 64 + sm * 16 + quad * 4 + r];
#pragma unroll
    for (int sn = 0; sn < 4; ++sn) {
      const int code = code_half * 64 + sn * 16 + m_row;
      const floatx4 v1 = acc1[sm][sn];
      const floatx4 v2 = acc2[sm][sn];
#pragma unroll
      for (int r = 0; r < 4; ++r) {
        const long tok = n0 + tok_half * 64 + sm * 16 + quad * 4 + r;
        const float sim = fmaf(v2[r], 0.000244140625f, v1[r]) * rnr[r];
        const float e = expf(sim / 0.05f);
        E[tok * KMEM + code] = e;
        rcol[sn] += e;
      }
    }
  }
#pragma unroll
  for (int sn = 0; sn < 4; ++sn) {
    rcol[sn] += __shfl_xor(rcol[sn], 16);
    rcol[sn] += __shfl_xor(rcol[sn], 32);
  }
  if (lane < 16) {
#pragma unroll
    for (int sn = 0; sn < 4; ++sn) red[wid][sn * 16 + lane] = rcol[sn];
  }
  __syncthreads();
  if (tid < KMEM) {
    const int ch = tid >> 6, cw = tid & 63;
    Rp[(long)blockIdx.x * KMEM + tid] =
        (double)(red[2 * ch][cw] + red[2 * ch + 1][cw]);
  }
}

// ---------------------------------------------------------------------------
// u update from Rp0 (1024 blocks): u[k] = 1/(K * sum_b Rp[b][k]). fp64 fixed
// order -> deterministic.
// ---------------------------------------------------------------------------
__global__ __launch_bounds__(1024) void u_kernel(const double* __restrict__ Rp,
                                                 int nblk,
                                                 float* __restrict__ u) {
  __shared__ double part[8][KMEM];
  const int k = threadIdx.x & 127;
  const int p = threadIdx.x >> 7;
  const int per = nblk >> 3;
  const int b0 = p * per;
  double s = 0.0;
  for (int b = 0; b < per; ++b) s += Rp[(long)(b0 + b) * KMEM + k];
  part[p][k] = s;
  __syncthreads();
  if (threadIdx.x < KMEM) {
    double t = 0.0;
#pragma unroll
    for (int g = 0; g < 8; ++g) t += part[g][k];
    u[k] = (float)(1.0 / (128.0 * t));
  }
}

// ---------------------------------------------------------------------------
// cv pass 1: u given directly. colsum C = dot(E_row, u); v = 1/(N*C);
// Rp_out[k] += E[n][k]*v.
// ---------------------------------------------------------------------------
__global__ __launch_bounds__(256) void cv1_kernel(const float* __restrict__ E,
                                                  const float* __restrict__ u,
                                                  double* __restrict__ Rp) {
  __shared__ double R2[8][KMEM];
  const int tid = threadIdx.x;
  const int kq = (tid & 31) * 4;
  const int tg = tid >> 5;
  const float4 u4 = *(const float4*)&u[kq];
  double r0 = 0, r1 = 0, r2 = 0, r3 = 0;
  const long n0 = (long)blockIdx.x * 512;
  for (int it = 0; it < 64; ++it) {
    const long n = n0 + it * 8 + tg;
    const float4 e = *(const float4*)&E[n * KMEM + kq];
    double c = (double)e.x * u4.x + (double)e.y * u4.y +
               (double)e.z * u4.z + (double)e.w * u4.w;
#pragma unroll
    for (int off = 1; off < 32; off <<= 1) c += __shfl_xor(c, off);
    const float v = (float)(1.0 / (131072.0 * c));
    r0 += (double)(e.x * v);
    r1 += (double)(e.y * v);
    r2 += (double)(e.z * v);
    r3 += (double)(e.w * v);
  }
  R2[tg][kq + 0] = r0;
  R2[tg][kq + 1] = r1;
  R2[tg][kq + 2] = r2;
  R2[tg][kq + 3] = r3;
  __syncthreads();
  if (tid < KMEM) {
    double s = 0.0;
#pragma unroll
    for (int g = 0; g < 8; ++g) s += R2[g][tid];
    Rp[(long)blockIdx.x * KMEM + tid] = s;
  }
}

// ---------------------------------------------------------------------------
// cv pass 2: reduce u inline from Rp_prev (256 x 128 doubles, L2-resident),
// then same as cv1.
// ---------------------------------------------------------------------------
__global__ __launch_bounds__(256) void cv2_kernel(
    const float* __restrict__ E, const double* __restrict__ Rp_prev,
    double* __restrict__ Rp) {
  __shared__ double us2[2][KMEM];
  __shared__ float u_s[KMEM];
  __shared__ double R2[8][KMEM];
  const int tid = threadIdx.x;
  {
    const int k = tid & 127;
    const int hf = tid >> 7;
    double s = 0.0;
    for (int b = hf * 128; b < hf * 128 + 128; ++b)
      s += Rp_prev[(long)b * KMEM + k];
    us2[hf][k] = s;
  }
  __syncthreads();
  if (tid < KMEM)
    u_s[tid] = (float)(1.0 / (128.0 * (us2[0][tid] + us2[1][tid])));
  __syncthreads();
  const int kq = (tid & 31) * 4;
  const int tg = tid >> 5;
  const float4 u4 = *(const float4*)&u_s[kq];
  double r0 = 0, r1 = 0, r2 = 0, r3 = 0;
  const long n0 = (long)blockIdx.x * 512;
  for (int it = 0; it < 64; ++it) {
    const long n = n0 + it * 8 + tg;
    const float4 e = *(const float4*)&E[n * KMEM + kq];
    double c = (double)e.x * u4.x + (double)e.y * u4.y +
               (double)e.z * u4.z + (double)e.w * u4.w;
#pragma unroll
    for (int off = 1; off < 32; off <<= 1) c += __shfl_xor(c, off);
    const float v = (float)(1.0 / (131072.0 * c));
    r0 += (double)(e.x * v);
    r1 += (double)(e.y * v);
    r2 += (double)(e.z * v);
    r3 += (double)(e.w * v);
  }
  R2[tg][kq + 0] = r0;
  R2[tg][kq + 1] = r1;
  R2[tg][kq + 2] = r2;
  R2[tg][kq + 3] = r3;
  __syncthreads();
  if (tid < KMEM) {
    double s = 0.0;
#pragma unroll
    for (int g = 0; g < 8; ++g) s += R2[g][tid];
    Rp[(long)blockIdx.x * KMEM + tid] = s;
  }
}

// ---------------------------------------------------------------------------
// argmax over k of E[n][k]*u3[k]; u3 reduced inline from Rp2. First-index
// tiebreak matches np.argmax.
// ---------------------------------------------------------------------------
__global__ __launch_bounds__(256) void argmax_kernel(
    const float* __restrict__ E, const double* __restrict__ Rp_prev,
    int* __restrict__ idx) {
  __shared__ double us2[2][KMEM];
  __shared__ float u_s[KMEM];
  const int tid = threadIdx.x;
  {
    const int k = tid & 127;
    const int hf = tid >> 7;
    double s = 0.0;
    for (int b = hf * 128; b < hf * 128 + 128; ++b)
      s += Rp_prev[(long)b * KMEM + k];
    us2[hf][k] = s;
  }
  __syncthreads();
  if (tid < KMEM)
    u_s[tid] = (float)(1.0 / (128.0 * (us2[0][tid] + us2[1][tid])));
  __syncthreads();
  const int kq = (tid & 31) * 4;
  const int tg = tid >> 5;
  const float4 u4 = *(const float4*)&u_s[kq];
  const long n0 = (long)blockIdx.x * 512;
  for (int it = 0; it < 64; ++it) {
    const long n = n0 + it * 8 + tg;
    const float4 e = *(const float4*)&E[n * KMEM + kq];
    float bv = e.x * u4.x;
    int bi = kq;
    float p = e.y * u4.y;
    if (p > bv) { bv = p; bi = kq + 1; }
    p = e.z * u4.z;
    if (p > bv) { bv = p; bi = kq + 2; }
    p = e.w * u4.w;
    if (p > bv) { bv = p; bi = kq + 3; }
#pragma unroll
    for (int off = 1; off < 32; off <<= 1) {
      const float ov = __shfl_xor(bv, off);
      const int oi = __shfl_xor(bi, off);
      if (ov > bv || (ov == bv && oi < bi)) { bv = ov; bi = oi; }
    }
    if ((tid & 31) == 0) idx[n] = bi;
  }
}

// ---------------------------------------------------------------------------
// out = (proj + glu_table[idx]) * 0.5, coalesced float4 stream.
// ---------------------------------------------------------------------------
__global__ __launch_bounds__(256) void out_kernel(
    const float* __restrict__ proj, const float* __restrict__ tab,
    const int* __restrict__ idx, float* __restrict__ out) {
  const long base = (long)blockIdx.x * 3072;
#pragma unroll
  for (int j = 0; j < 12; ++j) {
    const long f = base + j * 256 + threadIdx.x;  // float4 index
    const int t = (int)(f / 48);                  // 48 float4 per token row
    const int r = (int)(f - (long)t * 48);
    const int id = idx[t];
    const float4 p = *(const float4*)&proj[f * 4];
    const float4 tb = *(const float4*)&tab[id * DDIM + r * 4];
    float4 o;
    o.x = (p.x + tb.x) * 0.5f;
    o.y = (p.y + tb.y) * 0.5f;
    o.z = (p.z + tb.z) * 0.5f;
    o.w = (p.w + tb.w) * 0.5f;
    *(float4*)&out[f * 4] = o;
  }
}

extern "C" void kernel_launch(void* const* d_in, const int* in_sizes, int n_in,
                              void* d_out, int out_size, void* d_ws,
                              size_t ws_size, hipStream_t stream) {
  const float* proj = (const float*)d_in[0];
  const float* mb = (const float*)d_in[1];
  const float* W = (const float*)d_in[2];
  const float* bias = (const float*)d_in[3];
  float* out = (float*)d_out;
  char* ws = (char*)d_ws;
  // ws layout (~1.77 MB total; Rp1/Rp2 overlay the dead Rp0 region)
  float* tab = (float*)(ws);                       // 98304 B
  _Float16* bhi = (_Float16*)(ws + 98304);         // 49152 B
  _Float16* blo = (_Float16*)(ws + 147456);        // 49152 B
  double* Rp0 = (double*)(ws + 196608);            // 1 MiB (1024x128 fp64)
  double* Rp1 = (double*)(ws + 196608);            // overlays Rp0 (dead)
  double* Rp2 = (double*)(ws + 458752);            // 256 KiB
  float* u1 = (float*)(ws + 1245184);              // 512 B
  int* idx = (int*)(ws + 1245696);                 // 512 KiB
  // E (N x K fp32 = 64 MiB) lives in d_out scratch; consumed before out write.
  float* E = out;

  prep_kernel<<<KMEM, DDIM, 0, stream>>>(mb, W, bias, bhi, blo, tab);
  sim_kernel<<<1024, 256, 0, stream>>>(proj, bhi, blo, E, Rp0);
  u_kernel<<<1, 1024, 0, stream>>>(Rp0, 1024, u1);
  cv1_kernel<<<256, 256, 0, stream>>>(E, u1, Rp1);
  cv2_kernel<<<256, 256, 0, stream>>>(E, Rp1, Rp2);
  argmax_kernel<<<256, 256, 0, stream>>>(E, Rp2, idx);
  out_kernel<<<2048, 256, 0, stream>>>(proj, tab, idx, out);
}

// Round 3
// 290.285 us; speedup vs baseline: 1.9294x; 1.5654x over previous
//
#include <hip/hip_runtime.h>

#define NTOK  131072
#define DDIM  192
#define KMEM  128
#define TWOD  384
#define NBLK  1024   // blocks in sim / cv / argmax grids (tokens per block = 128)

typedef _Float16 half8 __attribute__((ext_vector_type(8)));
typedef float   floatx4 __attribute__((ext_vector_type(4)));

// ---------------------------------------------------------------------------
// prep: L2-normalize mem_bank rows -> fp16x2 split (hi, lo*4096) global arrays;
// precompute GLU(mem_bank) table (K distinct rows only).
// ---------------------------------------------------------------------------
__global__ __launch_bounds__(192) void prep_kernel(
    const float* __restrict__ mb, const float* __restrict__ W,
    const float* __restrict__ bias, _Float16* __restrict__ bhi,
    _Float16* __restrict__ blo, float* __restrict__ tab) {
  __shared__ float row[DDIM];
  __shared__ float red[DDIM];
  __shared__ float s_rn;
  const int k = blockIdx.x;
  const int t = threadIdx.x;  // 0..191
  float m = mb[k * DDIM + t];
  row[t] = m;
  red[t] = m * m;
  __syncthreads();
  if (t == 0) {
    float s = 0.f;
    for (int i = 0; i < DDIM; ++i) s += red[i];
    s_rn = 1.0f / sqrtf(fmaxf(s, 1e-12f));
  }
  __syncthreads();
  const float mn = m * s_rn;
  const _Float16 hh = (_Float16)mn;
  const float lo = (mn - (float)hh) * 4096.0f;
  bhi[k * DDIM + t] = hh;
  blo[k * DDIM + t] = (_Float16)lo;
  float a = bias[t], g = bias[DDIM + t];
  for (int d = 0; d < DDIM; ++d) {
    float r = row[d];
    a = fmaf(r, W[d * TWOD + t], a);
    g = fmaf(r, W[d * TWOD + DDIM + t], g);
  }
  float sg = 1.0f / (1.0f + expf(-g));
  tab[k * DDIM + t] = a * sg;
}

// ---------------------------------------------------------------------------
// sim: E[n][k] = exp(cos_sim/0.05) via fp16x2 MFMA (16x16x32_f16).
// Row-sum partials written k-major: RpT[k][block].
// ---------------------------------------------------------------------------
#define LSTR 40
__global__ __launch_bounds__(256, 2) void sim_kernel(
    const float* __restrict__ proj, const _Float16* __restrict__ bhi_g,
    const _Float16* __restrict__ blo_g, float* __restrict__ E,
    double* __restrict__ RpT) {
  __shared__ _Float16 Ahi[128 * LSTR];
  __shared__ _Float16 Alo[128 * LSTR];
  __shared__ _Float16 Bhi[128 * LSTR];
  __shared__ _Float16 Blo[128 * LSTR];
  __shared__ float rn_s[128];
  __shared__ float red[4][64];
  const int tid = threadIdx.x;
  const int lane = tid & 63;
  const int wid = tid >> 6;
  const int tok_half = wid & 1;
  const int code_half = wid >> 1;
  const long n0 = (long)blockIdx.x * 128;
  const int st_tok = tid >> 1;   // staging: token row 0..127
  const int st_h = tid & 1;      // staging: which 16-float half of the chunk

  floatx4 acc1[4][4];
  floatx4 acc2[4][4];
#pragma unroll
  for (int i = 0; i < 4; ++i)
#pragma unroll
    for (int j = 0; j < 4; ++j) {
      acc1[i][j] = (floatx4)0.0f;
      acc2[i][j] = (floatx4)0.0f;
    }
  float nsq = 0.f;

  const int m_row = lane & 15;
  const int quad = lane >> 4;
  const int kcol = quad * 8;

  for (int c = 0; c < 6; ++c) {
    // ---- stage A (proj chunk, fp32 -> hi/lo halfs) ----
    {
      const float* src = &proj[(n0 + st_tok) * DDIM + c * 32 + st_h * 16];
      float4 p0 = *(const float4*)(src + 0);
      float4 p1 = *(const float4*)(src + 4);
      float4 p2 = *(const float4*)(src + 8);
      float4 p3 = *(const float4*)(src + 12);
      float xs[16] = {p0.x, p0.y, p0.z, p0.w, p1.x, p1.y, p1.z, p1.w,
                      p2.x, p2.y, p2.z, p2.w, p3.x, p3.y, p3.z, p3.w};
      half8 h0, h1, l0, l1;
#pragma unroll
      for (int i = 0; i < 8; ++i) {
        float x = xs[i];
        nsq = fmaf(x, x, nsq);
        _Float16 hh = (_Float16)x;
        h0[i] = hh;
        l0[i] = (_Float16)((x - (float)hh) * 4096.0f);
      }
#pragma unroll
      for (int i = 0; i < 8; ++i) {
        float x = xs[8 + i];
        nsq = fmaf(x, x, nsq);
        _Float16 hh = (_Float16)x;
        h1[i] = hh;
        l1[i] = (_Float16)((x - (float)hh) * 4096.0f);
      }
      const int lb = st_tok * LSTR + st_h * 16;
      *(half8*)&Ahi[lb] = h0;
      *(half8*)&Ahi[lb + 8] = h1;
      *(half8*)&Alo[lb] = l0;
      *(half8*)&Alo[lb + 8] = l1;
      // ---- stage B (preconverted halfs, straight copy) ----
      const int gb = st_tok * DDIM + c * 32 + st_h * 16;
      *(half8*)&Bhi[lb] = *(const half8*)&bhi_g[gb];
      *(half8*)&Bhi[lb + 8] = *(const half8*)&bhi_g[gb + 8];
      *(half8*)&Blo[lb] = *(const half8*)&blo_g[gb];
      *(half8*)&Blo[lb + 8] = *(const half8*)&blo_g[gb + 8];
    }
    __syncthreads();
    // ---- MFMA over this k-chunk (K=32, one 16x16x32 step) ----
    half8 a_hi[4], a_lo[4];
#pragma unroll
    for (int sm = 0; sm < 4; ++sm) {
      const int ar = (tok_half * 64 + sm * 16 + m_row) * LSTR + kcol;
      a_hi[sm] = *(const half8*)&Ahi[ar];
      a_lo[sm] = *(const half8*)&Alo[ar];
    }
#pragma unroll
    for (int sn = 0; sn < 4; ++sn) {
      const int br = (code_half * 64 + sn * 16 + m_row) * LSTR + kcol;
      half8 b_hi = *(const half8*)&Bhi[br];
      half8 b_lo = *(const half8*)&Blo[br];
#pragma unroll
      for (int sm = 0; sm < 4; ++sm) {
        acc1[sm][sn] =
            __builtin_amdgcn_mfma_f32_16x16x32_f16(a_hi[sm], b_hi, acc1[sm][sn], 0, 0, 0);
        acc2[sm][sn] =
            __builtin_amdgcn_mfma_f32_16x16x32_f16(a_hi[sm], b_lo, acc2[sm][sn], 0, 0, 0);
        acc2[sm][sn] =
            __builtin_amdgcn_mfma_f32_16x16x32_f16(a_lo[sm], b_hi, acc2[sm][sn], 0, 0, 0);
      }
    }
    __syncthreads();
  }
  // token norms: thread pair (t, t^1) covered complementary halves
  nsq += __shfl_xor(nsq, 1);
  if ((tid & 1) == 0) rn_s[st_tok] = 1.0f / sqrtf(fmaxf(nsq, 1e-12f));
  __syncthreads();

  // ---- epilogue: sim -> exp, store E, per-wave column sums ----
  float rcol[4] = {0.f, 0.f, 0.f, 0.f};
#pragma unroll
  for (int sm = 0; sm < 4; ++sm) {
    float rnr[4];
#pragma unroll
    for (int r = 0; r < 4; ++r)
      rnr[r] = rn_s[tok_half * 64 + sm * 16 + quad * 4 + r];
#pragma unroll
    for (int sn = 0; sn < 4; ++sn) {
      const int code = code_half * 64 + sn * 16 + m_row;
      const floatx4 v1 = acc1[sm][sn];
      const floatx4 v2 = acc2[sm][sn];
#pragma unroll
      for (int r = 0; r < 4; ++r) {
        const long tok = n0 + tok_half * 64 + sm * 16 + quad * 4 + r;
        const float sim = fmaf(v2[r], 0.000244140625f, v1[r]) * rnr[r];
        const float e = expf(sim / 0.05f);
        E[tok * KMEM + code] = e;
        rcol[sn] += e;
      }
    }
  }
#pragma unroll
  for (int sn = 0; sn < 4; ++sn) {
    rcol[sn] += __shfl_xor(rcol[sn], 16);
    rcol[sn] += __shfl_xor(rcol[sn], 32);
  }
  if (lane < 16) {
#pragma unroll
    for (int sn = 0; sn < 4; ++sn) red[wid][sn * 16 + lane] = rcol[sn];
  }
  __syncthreads();
  if (tid < KMEM) {
    const int ch = tid >> 6, cw = tid & 63;
    RpT[(long)tid * NBLK + blockIdx.x] =
        (double)(red[2 * ch][cw] + red[2 * ch + 1][cw]);
  }
}

// ---------------------------------------------------------------------------
// u update: u[k] = 1/(K * sum_b RpT[k][b]). One block per k, coalesced,
// deterministic fixed-order fp64.
// ---------------------------------------------------------------------------
__global__ __launch_bounds__(256) void u_kernel(const double* __restrict__ RpT,
                                                float* __restrict__ u) {
  __shared__ double wred[4];
  const int k = blockIdx.x;
  const int t = threadIdx.x;
  double s = 0.0;
#pragma unroll
  for (int j = 0; j < NBLK / 256; ++j) s += RpT[(long)k * NBLK + j * 256 + t];
#pragma unroll
  for (int off = 1; off < 64; off <<= 1) s += __shfl_xor(s, off);
  if ((t & 63) == 0) wred[t >> 6] = s;
  __syncthreads();
  if (t == 0)
    u[k] = (float)(1.0 / (128.0 * (wred[0] + wred[1] + wred[2] + wred[3])));
}

// ---------------------------------------------------------------------------
// cv: per token colsum C = dot(E_row, u); v = 1/(N*C); RpT[k][blk] += E*v.
// 8 lanes per token (16 k's each), 3-level shfl, 128 tokens per block.
// ---------------------------------------------------------------------------
__global__ __launch_bounds__(256) void cv_kernel(const float* __restrict__ E,
                                                 const float* __restrict__ u,
                                                 double* __restrict__ RpT) {
  __shared__ double part[4][KMEM];
  const int tid = threadIdx.x;
  const int l = tid & 7;    // lane-in-token
  const int ts = tid >> 3;  // token slot 0..31
  const long n0 = (long)blockIdx.x * 128;
  float4 u4[4];
#pragma unroll
  for (int j = 0; j < 4; ++j) u4[j] = *(const float4*)&u[l * 16 + j * 4];
  double r[16];
#pragma unroll
  for (int i = 0; i < 16; ++i) r[i] = 0.0;
#pragma unroll
  for (int it = 0; it < 4; ++it) {
    const long n = n0 + it * 32 + ts;
    const float* Er = &E[n * KMEM + l * 16];
    const float4 e0 = *(const float4*)(Er + 0);
    const float4 e1 = *(const float4*)(Er + 4);
    const float4 e2 = *(const float4*)(Er + 8);
    const float4 e3 = *(const float4*)(Er + 12);
    double c = (double)e0.x * u4[0].x + (double)e0.y * u4[0].y +
               (double)e0.z * u4[0].z + (double)e0.w * u4[0].w +
               (double)e1.x * u4[1].x + (double)e1.y * u4[1].y +
               (double)e1.z * u4[1].z + (double)e1.w * u4[1].w +
               (double)e2.x * u4[2].x + (double)e2.y * u4[2].y +
               (double)e2.z * u4[2].z + (double)e2.w * u4[2].w +
               (double)e3.x * u4[3].x + (double)e3.y * u4[3].y +
               (double)e3.z * u4[3].z + (double)e3.w * u4[3].w;
    c += __shfl_xor(c, 1);
    c += __shfl_xor(c, 2);
    c += __shfl_xor(c, 4);
    const float v = (float)(1.0 / (131072.0 * c));
    r[0] += (double)(e0.x * v);
    r[1] += (double)(e0.y * v);
    r[2] += (double)(e0.z * v);
    r[3] += (double)(e0.w * v);
    r[4] += (double)(e1.x * v);
    r[5] += (double)(e1.y * v);
    r[6] += (double)(e1.z * v);
    r[7] += (double)(e1.w * v);
    r[8] += (double)(e2.x * v);
    r[9] += (double)(e2.y * v);
    r[10] += (double)(e2.z * v);
    r[11] += (double)(e2.w * v);
    r[12] += (double)(e3.x * v);
    r[13] += (double)(e3.y * v);
    r[14] += (double)(e3.z * v);
    r[15] += (double)(e3.w * v);
  }
  // reduce across the 4 token-slots within each wave (lanes sharing l)
#pragma unroll
  for (int i = 0; i < 16; ++i) {
    r[i] += __shfl_xor(r[i], 8);
    r[i] += __shfl_xor(r[i], 16);
    r[i] += __shfl_xor(r[i], 32);
  }
  if ((tid & 63) < 8) {
    const int w = tid >> 6;
#pragma unroll
    for (int i = 0; i < 16; ++i) part[w][l * 16 + i] = r[i];
  }
  __syncthreads();
  if (tid < KMEM) {
    const double s = part[0][tid] + part[1][tid] + part[2][tid] + part[3][tid];
    RpT[(long)tid * NBLK + blockIdx.x] = s;
  }
}

// ---------------------------------------------------------------------------
// argmax over k of E[n][k]*u[k]. 8 lanes/token, first-index tiebreak.
// ---------------------------------------------------------------------------
__global__ __launch_bounds__(256) void argmax_kernel(
    const float* __restrict__ E, const float* __restrict__ u,
    int* __restrict__ idx) {
  const int tid = threadIdx.x;
  const int l = tid & 7;
  const int ts = tid >> 3;
  const long n0 = (long)blockIdx.x * 128;
  float4 u4[4];
#pragma unroll
  for (int j = 0; j < 4; ++j) u4[j] = *(const float4*)&u[l * 16 + j * 4];
#pragma unroll
  for (int it = 0; it < 4; ++it) {
    const long n = n0 + it * 32 + ts;
    const float* Er = &E[n * KMEM + l * 16];
    const float4 e0 = *(const float4*)(Er + 0);
    const float4 e1 = *(const float4*)(Er + 4);
    const float4 e2 = *(const float4*)(Er + 8);
    const float4 e3 = *(const float4*)(Er + 12);
    float p[16];
    p[0] = e0.x * u4[0].x; p[1] = e0.y * u4[0].y;
    p[2] = e0.z * u4[0].z; p[3] = e0.w * u4[0].w;
    p[4] = e1.x * u4[1].x; p[5] = e1.y * u4[1].y;
    p[6] = e1.z * u4[1].z; p[7] = e1.w * u4[1].w;
    p[8] = e2.x * u4[2].x; p[9] = e2.y * u4[2].y;
    p[10] = e2.z * u4[2].z; p[11] = e2.w * u4[2].w;
    p[12] = e3.x * u4[3].x; p[13] = e3.y * u4[3].y;
    p[14] = e3.z * u4[3].z; p[15] = e3.w * u4[3].w;
    float bv = p[0];
    int bi = l * 16;
#pragma unroll
    for (int i = 1; i < 16; ++i) {
      if (p[i] > bv) { bv = p[i]; bi = l * 16 + i; }
    }
#pragma unroll
    for (int off = 1; off < 8; off <<= 1) {
      const float ov = __shfl_xor(bv, off);
      const int oi = __shfl_xor(bi, off);
      if (ov > bv || (ov == bv && oi < bi)) { bv = ov; bi = oi; }
    }
    if (l == 0) idx[n] = bi;
  }
}

// ---------------------------------------------------------------------------
// out = (proj + glu_table[idx]) * 0.5, coalesced float4 stream.
// ---------------------------------------------------------------------------
__global__ __launch_bounds__(256) void out_kernel(
    const float* __restrict__ proj, const float* __restrict__ tab,
    const int* __restrict__ idx, float* __restrict__ out) {
  const long base = (long)blockIdx.x * 3072;
#pragma unroll
  for (int j = 0; j < 12; ++j) {
    const long f = base + j * 256 + threadIdx.x;  // float4 index
    const int t = (int)(f / 48);                  // 48 float4 per token row
    const int r = (int)(f - (long)t * 48);
    const int id = idx[t];
    const float4 p = *(const float4*)&proj[f * 4];
    const float4 tb = *(const float4*)&tab[id * DDIM + r * 4];
    float4 o;
    o.x = (p.x + tb.x) * 0.5f;
    o.y = (p.y + tb.y) * 0.5f;
    o.z = (p.z + tb.z) * 0.5f;
    o.w = (p.w + tb.w) * 0.5f;
    *(float4*)&out[f * 4] = o;
  }
}

extern "C" void kernel_launch(void* const* d_in, const int* in_sizes, int n_in,
                              void* d_out, int out_size, void* d_ws,
                              size_t ws_size, hipStream_t stream) {
  const float* proj = (const float*)d_in[0];
  const float* mb = (const float*)d_in[1];
  const float* W = (const float*)d_in[2];
  const float* bias = (const float*)d_in[3];
  float* out = (float*)d_out;
  char* ws = (char*)d_ws;
  // ws layout (~2.7 MB total; RpA/RpB alternate across Sinkhorn iterations)
  float* tab = (float*)(ws);                  // 98304 B
  _Float16* bhi = (_Float16*)(ws + 98304);    // 49152 B
  _Float16* blo = (_Float16*)(ws + 147456);   // 49152 B
  float* u1 = (float*)(ws + 196608);          // 512 B
  float* u2 = (float*)(ws + 197120);          // 512 B
  float* u3 = (float*)(ws + 197632);          // 512 B
  int* idx = (int*)(ws + 198144);             // 524288 B
  double* RpA = (double*)(ws + 722432);       // 1 MiB (128 x 1024 fp64)
  double* RpB = (double*)(ws + 1771008);      // 1 MiB
  // E (N x K fp32 = 64 MiB) lives in d_out scratch; consumed before out write.
  float* E = out;

  prep_kernel<<<KMEM, DDIM, 0, stream>>>(mb, W, bias, bhi, blo, tab);
  sim_kernel<<<NBLK, 256, 0, stream>>>(proj, bhi, blo, E, RpA);
  u_kernel<<<KMEM, 256, 0, stream>>>(RpA, u1);
  cv_kernel<<<NBLK, 256, 0, stream>>>(E, u1, RpB);
  u_kernel<<<KMEM, 256, 0, stream>>>(RpB, u2);
  cv_kernel<<<NBLK, 256, 0, stream>>>(E, u2, RpA);
  u_kernel<<<KMEM, 256, 0, stream>>>(RpA, u3);
  argmax_kernel<<<NBLK, 256, 0, stream>>>(E, u3, idx);
  out_kernel<<<2048, 256, 0, stream>>>(proj, tab, idx, out);
}